// Round 12
// baseline (96.885 us; speedup 1.0000x reference)
//
#include <hip/hip_runtime.h>

// Camera ISP fused: mosaic -> 3x3 gauss blur -> 17-knot LUT -> +noise ->
// sparse 5x5 demosaic -> bayer-parity select -> clip.
// Round 11: R10 row-pair prefetch pipeline, TDS 16 -> 8 with
// __launch_bounds__(256,4): 4096 waves (4/SIMD) AND loads prefetched one
// fat-iteration ahead. (R7 tested TLP without prefetch: regressed; R9/R10
// tested prefetch without TLP: 41 us. This is the untested combination.)

#define TDS 8      // output rows per wave

typedef float f4u __attribute__((ext_vector_type(4), aligned(16)));

struct HB { float hb0, hb1, hb2, hb3, hh0, hh1; };
struct MR { f4u a, b, ae, be; };
struct NZ { f4u z; float ze0, ze1; };

__device__ __forceinline__ int refl(int i, int n) {
    return i < 0 ? -i : (i >= n ? 2 * n - 2 - i : i);
}

__device__ __forceinline__ float clip01(float x) {
    return fminf(fmaxf(x * (1.0f / 255.0f), 0.0f), 1.0f);
}

__global__ __launch_bounds__(256, 4) void camera_kernel(
    const float* __restrict__ im, const float* __restrict__ yp,
    const float* __restrict__ noise, float* __restrict__ out,
    int H, int W)
{
    __shared__ float2 s_tab[4][48];   // per-wave LUT copy (no block barrier)

    const int tid  = threadIdx.x;
    const int wv   = tid >> 6;
    const int lane = tid & 63;
    const int b    = blockIdx.z;

    const int stripes = W >> 8;                  // 256-px stripes (2)
    const int slot    = blockIdx.x * 4 + wv;
    const int stripe  = slot % stripes;
    const int gy0     = (slot / stripes) * TDS;  // even
    const int gx0     = stripe << 8;             // even
    const int x0      = gx0 + 4 * lane;

    const size_t HW = (size_t)H * W;
    const float* p0  = im + (size_t)b * 3 * HW;  // ch0 plane
    const float* p1  = p0 + HW;                  // ch1 plane
    const float* nzb = noise + (size_t)b * HW;

    if (lane < 48) {
        int ch = lane >> 4, i = lane & 15;
        s_tab[wv][lane] = make_float2(yp[ch * 17 + i], yp[ch * 17 + i + 1]);
    }
    asm volatile("s_waitcnt lgkmcnt(0)" ::: "memory");
    const float2* tabw = s_tab[wv];

    const bool l0   = (lane == 0), l63 = (lane == 63);
    const bool lInt = l0  && (gx0 != 0);         // interior stripe boundary
    const bool rInt = l63 && (x0 + 4 != W);
    const bool eInt = lInt || rInt;
    const bool eAny = l0 || l63;
    const int  xe   = l0 ? x0 - 4 : x0 + 4;      // edge mosaic halo base
    const int  xen  = l0 ? x0 - 2 : x0 + 4;      // edge noise halo base

    const float g0 = 0.04038794f;   // 1D gauss tail (sigma=0.4, normalized)
    const float g1 = 0.91922413f;   // 1D gauss center

    auto itp = [&](float tv, int ch) -> float {  // LUT interp, input x16 scale
        float s = tv * 16.0f;
        int i = (int)s; i = i < 0 ? 0 : (i > 15 ? 15 : i);
        float2 p = tabw[ch * 16 + i];
        return fmaf(s - (float)i, p.y - p.x, p.x);
    };

    // ---- raw loads (issue-only) ----
    auto ldmos = [&](int t) -> MR {
        MR m;
        int yr = refl(t, H);                     // parity-preserving
        const float* pe = (t & 1) ? p0 : p1;     // plane for even cols
        const float* re = pe + (size_t)yr * W;
        const float* ro = re + HW;               // plane for odd cols
        m.a = *(const f4u*)(re + x0);
        m.b = *(const f4u*)(ro + x0);
        m.ae = m.a; m.be = m.b;                  // defined default
        if (eInt) {
            m.ae = *(const f4u*)(re + xe);
            m.be = *(const f4u*)(ro + xe);
        }
        return m;
    };
    auto ldnz = [&](int t) -> NZ {
        NZ z;
        int yr = refl(t, H);
        const float* nzr = nzb + (size_t)yr * W;
        z.z = *(const f4u*)(nzr + x0);
        z.ze0 = 0.f; z.ze1 = 0.f;
        if (eInt) {
            float2 e = *(const float2*)(nzr + xen);
            z.ze0 = e.x; z.ze1 = e.y;
        }
        return z;
    };

    // ---- hblur from raw row (shfl + fma) ----
    auto hblur = [&](const MR& q) -> HB {
        float m0 = q.a.x, m1 = q.b.y, m2 = q.a.z, m3 = q.b.w;  // cols x0..x0+3
        float ml = __shfl_up(m3, 1, 64);         // col x0-1
        float mr = __shfl_down(m0, 1, 64);       // col x0+4
        float me0 = q.ae.x, me1 = q.be.y, me2 = q.ae.z, me3 = q.be.w;
        if (l0)  ml = lInt ? me3 : m1;           // reflect: col -1 -> 1
        if (l63) mr = rInt ? me0 : m2;           // reflect: col W -> W-2
        HB h;
        h.hb0 = fmaf(g0, ml + m1, g1 * m0);
        h.hb1 = fmaf(g0, m0 + m2, g1 * m1);
        h.hb2 = fmaf(g0, m1 + m3, g1 * m2);
        h.hb3 = fmaf(g0, m2 + mr, g1 * m3);
        float hL0 = fmaf(g0, me1 + me3, g1 * me2);
        float hL1 = fmaf(g0, me2 + m0,  g1 * me3);
        float hR0 = fmaf(g0, m3 + me1,  g1 * me0);
        float hR1 = fmaf(g0, me0 + me2, g1 * me1);
        h.hh0 = l0 ? hL0 : hR0;
        h.hh1 = l0 ? hL1 : hR1;
        return h;
    };

    // produce one noisy row (8-wide window incl. shfl halo) into rg[8]
    auto mknoisy = [&](const HB& a, const HB& bq, const HB& c,
                       const NZ& z, int chE, float* rg) {
        float tb0 = fmaf(g0, a.hb0 + c.hb0, g1 * bq.hb0);
        float tb1 = fmaf(g0, a.hb1 + c.hb1, g1 * bq.hb1);
        float tb2 = fmaf(g0, a.hb2 + c.hb2, g1 * bq.hb2);
        float tb3 = fmaf(g0, a.hb3 + c.hb3, g1 * bq.hb3);
        float th0 = fmaf(g0, a.hh0 + c.hh0, g1 * bq.hh0);
        float th1 = fmaf(g0, a.hh1 + c.hh1, g1 * bq.hh1);
        const int chO = chE + 1;
        float c0 = itp(tb0, chE) + z.z.x;
        float c1 = itp(tb1, chO) + z.z.y;
        float c2 = itp(tb2, chE) + z.z.z;
        float c3 = itp(tb3, chO) + z.z.w;
        float e0 = 0.f, e1 = 0.f;
        if (eAny) { e0 = itp(th0, chE) + z.ze0; e1 = itp(th1, chO) + z.ze1; }
        float hl0 = __shfl_up(c2, 1, 64);
        float hl1 = __shfl_up(c3, 1, 64);
        float hr0 = __shfl_down(c0, 1, 64);
        float hr1 = __shfl_down(c1, 1, 64);
        if (l0)  { hl0 = lInt ? e0 : c2;  hl1 = lInt ? e1 : c1; }
        if (l63) { hr0 = rInt ? e0 : c2;  hr1 = rInt ? e1 : c1; }
        rg[0] = hl0; rg[1] = hl1; rg[2] = c0; rg[3] = c1;
        rg[4] = c2;  rg[5] = c3;  rg[6] = hr0; rg[7] = hr1;
    };

    // demosaic one row from 5 noisy-row windows; yO = row parity
    auto dem = [&](const float* u2, const float* u1, const float* ct,
                   const float* d1, const float* d2, bool yO,
                   float* Rv, float* Gv, float* Bv) {
        #pragma unroll
        for (int j = 0; j < 4; ++j) {
            const int cj = 2 + j;
            float c    = ct[cj];
            float ax1x = ct[cj - 1] + ct[cj + 1];
            float ax2x = ct[cj - 2] + ct[cj + 2];
            float ax1y = u1[cj] + d1[cj];
            float diag = u1[cj - 1] + u1[cj + 1] + d1[cj - 1] + d1[cj + 1];
            float ax2y = u2[cj] + d2[cj];
            const bool xO = (j & 1) != 0;
            float R, G, Bc;
            if (!yO && !xO) {        // p00: R=v, G=raw, B=h
                float hh = (0.5f * ax2y - diag - ax2x + 4.f * ax1x + 5.f * c) * 0.125f;
                float vv = (0.5f * ax2x - diag - ax2y + 4.f * ax1y + 5.f * c) * 0.125f;
                R = vv; G = c; Bc = hh;
            } else if (!yO && xO) {  // p01: R=d, G=g, B=raw
                float gg = (2.f * (ax1y + ax1x) - ax2y - ax2x + 4.f * c) * 0.125f;
                float dd = (2.f * diag - 1.5f * (ax2y + ax2x) + 6.f * c) * 0.125f;
                R = dd; G = gg; Bc = c;
            } else if (yO && !xO) {  // p10: R=raw, G=g, B=d
                float gg = (2.f * (ax1y + ax1x) - ax2y - ax2x + 4.f * c) * 0.125f;
                float dd = (2.f * diag - 1.5f * (ax2y + ax2x) + 6.f * c) * 0.125f;
                R = c; G = gg; Bc = dd;
            } else {                 // p11: R=h, G=raw, B=v
                float hh = (0.5f * ax2y - diag - ax2x + 4.f * ax1x + 5.f * c) * 0.125f;
                float vv = (0.5f * ax2x - diag - ax2y + 4.f * ax1y + 5.f * c) * 0.125f;
                R = hh; G = c; Bc = vv;
            }
            Rv[j] = clip01(R); Gv[j] = clip01(G); Bv[j] = clip01(Bc);
        }
    };

    float ring[3][2][8];                         // 3 pairs x 2 noisy rows x 8 cols
    // prologue: hblur rows gy0-3, gy0-2; prefetch t=0's raw groups
    HB hc0 = hblur(ldmos(gy0 - 3));
    HB hc1 = hblur(ldmos(gy0 - 2));
    MR mN0 = ldmos(gy0 - 1);
    MR mN1 = ldmos(gy0);
    NZ zN0 = ldnz(gy0 - 2);
    NZ zN1 = ldnz(gy0 - 1);
    const size_t outb = (size_t)b * 3 * HW;

    #pragma unroll
    for (int t = 0; t < TDS / 2 + 2; ++t) {      // 6 fat iterations
        MR mC0 = mN0, mC1 = mN1;                 // consume prefetched
        NZ zC0 = zN0, zC1 = zN1;
        if (t < TDS / 2 + 1) {                   // issue next-iter loads FIRST
            mN0 = ldmos(gy0 + 2 * t + 1);
            mN1 = ldmos(gy0 + 2 * t + 2);
            zN0 = ldnz(gy0 + 2 * t);
            zN1 = ldnz(gy0 + 2 * t + 1);
        }
        HB hn0 = hblur(mC0);                     // hblur row gy0-1+2t
        HB hn1 = hblur(mC1);                     // hblur row gy0+2t
        // noisy r0 = gy0-2+2t (even, chE=1): vblur(hc0, hc1, hn0)
        // noisy r1 = gy0-1+2t (odd,  chE=0): vblur(hc1, hn0, hn1)
        mknoisy(hc0, hc1, hn0, zC0, 1, ring[t % 3][0]);
        mknoisy(hc1, hn0, hn1, zC1, 0, ring[t % 3][1]);
        hc0 = hn0; hc1 = hn1;

        if (t >= 2) {                            // demosaic rows gy0+2t-4, +2t-3
            const int y0 = gy0 + 2 * t - 4;      // even
            float R0[4], G0[4], B0[4], R1[4], G1[4], B1[4];
            dem(ring[(t - 2) % 3][0], ring[(t - 2) % 3][1], ring[(t - 1) % 3][0],
                ring[(t - 1) % 3][1], ring[t % 3][0], false, R0, G0, B0);
            dem(ring[(t - 2) % 3][1], ring[(t - 1) % 3][0], ring[(t - 1) % 3][1],
                ring[t % 3][0], ring[t % 3][1], true, R1, G1, B1);
            // plane-major stores: 2-row contiguous bursts per plane
            size_t o = outb + (size_t)y0 * W + x0;
            *(f4u*)(out + o)              = (f4u){R0[0], R0[1], R0[2], R0[3]};
            *(f4u*)(out + o + W)          = (f4u){R1[0], R1[1], R1[2], R1[3]};
            *(f4u*)(out + o + HW)         = (f4u){G0[0], G0[1], G0[2], G0[3]};
            *(f4u*)(out + o + HW + W)     = (f4u){G1[0], G1[1], G1[2], G1[3]};
            *(f4u*)(out + o + 2 * HW)     = (f4u){B0[0], B0[1], B0[2], B0[3]};
            *(f4u*)(out + o + 2 * HW + W) = (f4u){B1[0], B1[1], B1[2], B1[3]};
        }
    }
}

extern "C" void kernel_launch(void* const* d_in, const int* in_sizes, int n_in,
                              void* d_out, int out_size, void* d_ws, size_t ws_size,
                              hipStream_t stream) {
    const float* im    = (const float*)d_in[0];
    const float* yp    = (const float*)d_in[1];
    const float* noise = (const float*)d_in[2];
    float* out = (float*)d_out;

    const int H = 512, W = 512;
    const int B = in_sizes[2] / (H * W);         // noise is (B,1,H,W)

    const int stripes = W / 256;                 // 2
    const int slots   = stripes * (H / TDS);     // 128 wave-slots per image
    dim3 grid(slots / 4, 1, B);                  // 4 waves per 256-thread block
    camera_kernel<<<grid, 256, 0, stream>>>(im, yp, noise, out, H, W);
}

// Round 13
// 44.200 us; speedup vs baseline: 2.1920x; 2.1920x over previous
//
#include <hip/hip_runtime.h>

// Camera ISP fused: mosaic -> 3x3 gauss blur -> 17-knot LUT -> +noise ->
// sparse 5x5 demosaic -> bayer-parity select -> clip.
// Round 12: R10 row-pair prefetch pipeline with TDS=8 and NO VGPR cap:
// __launch_bounds__(256,2) keeps the compiler at ~92 VGPR (<=128), so the
// HARDWARE grants 4 waves/SIMD from the 4096-wave grid. R11's (256,4)
// mistake capped VGPR at 64 and spilled (WRITE 181MB); this is the same
// experiment without the cap.

#define TDS 8      // output rows per wave

typedef float f4u __attribute__((ext_vector_type(4), aligned(16)));

struct HB { float hb0, hb1, hb2, hb3, hh0, hh1; };
struct MR { f4u a, b, ae, be; };
struct NZ { f4u z; float ze0, ze1; };

__device__ __forceinline__ int refl(int i, int n) {
    return i < 0 ? -i : (i >= n ? 2 * n - 2 - i : i);
}

__device__ __forceinline__ float clip01(float x) {
    return fminf(fmaxf(x * (1.0f / 255.0f), 0.0f), 1.0f);
}

__global__ __launch_bounds__(256, 2) void camera_kernel(
    const float* __restrict__ im, const float* __restrict__ yp,
    const float* __restrict__ noise, float* __restrict__ out,
    int H, int W)
{
    __shared__ float2 s_tab[4][48];   // per-wave LUT copy (no block barrier)

    const int tid  = threadIdx.x;
    const int wv   = tid >> 6;
    const int lane = tid & 63;
    const int b    = blockIdx.z;

    const int stripes = W >> 8;                  // 256-px stripes (2)
    const int slot    = blockIdx.x * 4 + wv;
    const int stripe  = slot % stripes;
    const int gy0     = (slot / stripes) * TDS;  // even
    const int gx0     = stripe << 8;             // even
    const int x0      = gx0 + 4 * lane;

    const size_t HW = (size_t)H * W;
    const float* p0  = im + (size_t)b * 3 * HW;  // ch0 plane
    const float* p1  = p0 + HW;                  // ch1 plane
    const float* nzb = noise + (size_t)b * HW;

    if (lane < 48) {
        int ch = lane >> 4, i = lane & 15;
        s_tab[wv][lane] = make_float2(yp[ch * 17 + i], yp[ch * 17 + i + 1]);
    }
    asm volatile("s_waitcnt lgkmcnt(0)" ::: "memory");
    const float2* tabw = s_tab[wv];

    const bool l0   = (lane == 0), l63 = (lane == 63);
    const bool lInt = l0  && (gx0 != 0);         // interior stripe boundary
    const bool rInt = l63 && (x0 + 4 != W);
    const bool eInt = lInt || rInt;
    const bool eAny = l0 || l63;
    const int  xe   = l0 ? x0 - 4 : x0 + 4;      // edge mosaic halo base
    const int  xen  = l0 ? x0 - 2 : x0 + 4;      // edge noise halo base

    const float g0 = 0.04038794f;   // 1D gauss tail (sigma=0.4, normalized)
    const float g1 = 0.91922413f;   // 1D gauss center

    auto itp = [&](float tv, int ch) -> float {  // LUT interp, input x16 scale
        float s = tv * 16.0f;
        int i = (int)s; i = i < 0 ? 0 : (i > 15 ? 15 : i);
        float2 p = tabw[ch * 16 + i];
        return fmaf(s - (float)i, p.y - p.x, p.x);
    };

    // ---- raw loads (issue-only) ----
    auto ldmos = [&](int t) -> MR {
        MR m;
        int yr = refl(t, H);                     // parity-preserving
        const float* pe = (t & 1) ? p0 : p1;     // plane for even cols
        const float* re = pe + (size_t)yr * W;
        const float* ro = re + HW;               // plane for odd cols
        m.a = *(const f4u*)(re + x0);
        m.b = *(const f4u*)(ro + x0);
        m.ae = m.a; m.be = m.b;                  // defined default
        if (eInt) {
            m.ae = *(const f4u*)(re + xe);
            m.be = *(const f4u*)(ro + xe);
        }
        return m;
    };
    auto ldnz = [&](int t) -> NZ {
        NZ z;
        int yr = refl(t, H);
        const float* nzr = nzb + (size_t)yr * W;
        z.z = *(const f4u*)(nzr + x0);
        z.ze0 = 0.f; z.ze1 = 0.f;
        if (eInt) {
            float2 e = *(const float2*)(nzr + xen);
            z.ze0 = e.x; z.ze1 = e.y;
        }
        return z;
    };

    // ---- hblur from raw row (shfl + fma) ----
    auto hblur = [&](const MR& q) -> HB {
        float m0 = q.a.x, m1 = q.b.y, m2 = q.a.z, m3 = q.b.w;  // cols x0..x0+3
        float ml = __shfl_up(m3, 1, 64);         // col x0-1
        float mr = __shfl_down(m0, 1, 64);       // col x0+4
        float me0 = q.ae.x, me1 = q.be.y, me2 = q.ae.z, me3 = q.be.w;
        if (l0)  ml = lInt ? me3 : m1;           // reflect: col -1 -> 1
        if (l63) mr = rInt ? me0 : m2;           // reflect: col W -> W-2
        HB h;
        h.hb0 = fmaf(g0, ml + m1, g1 * m0);
        h.hb1 = fmaf(g0, m0 + m2, g1 * m1);
        h.hb2 = fmaf(g0, m1 + m3, g1 * m2);
        h.hb3 = fmaf(g0, m2 + mr, g1 * m3);
        float hL0 = fmaf(g0, me1 + me3, g1 * me2);
        float hL1 = fmaf(g0, me2 + m0,  g1 * me3);
        float hR0 = fmaf(g0, m3 + me1,  g1 * me0);
        float hR1 = fmaf(g0, me0 + me2, g1 * me1);
        h.hh0 = l0 ? hL0 : hR0;
        h.hh1 = l0 ? hL1 : hR1;
        return h;
    };

    // produce one noisy row (8-wide window incl. shfl halo) into rg[8]
    auto mknoisy = [&](const HB& a, const HB& bq, const HB& c,
                       const NZ& z, int chE, float* rg) {
        float tb0 = fmaf(g0, a.hb0 + c.hb0, g1 * bq.hb0);
        float tb1 = fmaf(g0, a.hb1 + c.hb1, g1 * bq.hb1);
        float tb2 = fmaf(g0, a.hb2 + c.hb2, g1 * bq.hb2);
        float tb3 = fmaf(g0, a.hb3 + c.hb3, g1 * bq.hb3);
        float th0 = fmaf(g0, a.hh0 + c.hh0, g1 * bq.hh0);
        float th1 = fmaf(g0, a.hh1 + c.hh1, g1 * bq.hh1);
        const int chO = chE + 1;
        float c0 = itp(tb0, chE) + z.z.x;
        float c1 = itp(tb1, chO) + z.z.y;
        float c2 = itp(tb2, chE) + z.z.z;
        float c3 = itp(tb3, chO) + z.z.w;
        float e0 = 0.f, e1 = 0.f;
        if (eAny) { e0 = itp(th0, chE) + z.ze0; e1 = itp(th1, chO) + z.ze1; }
        float hl0 = __shfl_up(c2, 1, 64);
        float hl1 = __shfl_up(c3, 1, 64);
        float hr0 = __shfl_down(c0, 1, 64);
        float hr1 = __shfl_down(c1, 1, 64);
        if (l0)  { hl0 = lInt ? e0 : c2;  hl1 = lInt ? e1 : c1; }
        if (l63) { hr0 = rInt ? e0 : c2;  hr1 = rInt ? e1 : c1; }
        rg[0] = hl0; rg[1] = hl1; rg[2] = c0; rg[3] = c1;
        rg[4] = c2;  rg[5] = c3;  rg[6] = hr0; rg[7] = hr1;
    };

    // demosaic one row from 5 noisy-row windows; yO = row parity
    auto dem = [&](const float* u2, const float* u1, const float* ct,
                   const float* d1, const float* d2, bool yO,
                   float* Rv, float* Gv, float* Bv) {
        #pragma unroll
        for (int j = 0; j < 4; ++j) {
            const int cj = 2 + j;
            float c    = ct[cj];
            float ax1x = ct[cj - 1] + ct[cj + 1];
            float ax2x = ct[cj - 2] + ct[cj + 2];
            float ax1y = u1[cj] + d1[cj];
            float diag = u1[cj - 1] + u1[cj + 1] + d1[cj - 1] + d1[cj + 1];
            float ax2y = u2[cj] + d2[cj];
            const bool xO = (j & 1) != 0;
            float R, G, Bc;
            if (!yO && !xO) {        // p00: R=v, G=raw, B=h
                float hh = (0.5f * ax2y - diag - ax2x + 4.f * ax1x + 5.f * c) * 0.125f;
                float vv = (0.5f * ax2x - diag - ax2y + 4.f * ax1y + 5.f * c) * 0.125f;
                R = vv; G = c; Bc = hh;
            } else if (!yO && xO) {  // p01: R=d, G=g, B=raw
                float gg = (2.f * (ax1y + ax1x) - ax2y - ax2x + 4.f * c) * 0.125f;
                float dd = (2.f * diag - 1.5f * (ax2y + ax2x) + 6.f * c) * 0.125f;
                R = dd; G = gg; Bc = c;
            } else if (yO && !xO) {  // p10: R=raw, G=g, B=d
                float gg = (2.f * (ax1y + ax1x) - ax2y - ax2x + 4.f * c) * 0.125f;
                float dd = (2.f * diag - 1.5f * (ax2y + ax2x) + 6.f * c) * 0.125f;
                R = c; G = gg; Bc = dd;
            } else {                 // p11: R=h, G=raw, B=v
                float hh = (0.5f * ax2y - diag - ax2x + 4.f * ax1x + 5.f * c) * 0.125f;
                float vv = (0.5f * ax2x - diag - ax2y + 4.f * ax1y + 5.f * c) * 0.125f;
                R = hh; G = c; Bc = vv;
            }
            Rv[j] = clip01(R); Gv[j] = clip01(G); Bv[j] = clip01(Bc);
        }
    };

    float ring[3][2][8];                         // 3 pairs x 2 noisy rows x 8 cols
    // prologue: hblur rows gy0-3, gy0-2; prefetch t=0's raw groups
    HB hc0 = hblur(ldmos(gy0 - 3));
    HB hc1 = hblur(ldmos(gy0 - 2));
    MR mN0 = ldmos(gy0 - 1);
    MR mN1 = ldmos(gy0);
    NZ zN0 = ldnz(gy0 - 2);
    NZ zN1 = ldnz(gy0 - 1);
    const size_t outb = (size_t)b * 3 * HW;

    #pragma unroll
    for (int t = 0; t < TDS / 2 + 2; ++t) {      // 6 fat iterations
        MR mC0 = mN0, mC1 = mN1;                 // consume prefetched
        NZ zC0 = zN0, zC1 = zN1;
        if (t < TDS / 2 + 1) {                   // issue next-iter loads FIRST
            mN0 = ldmos(gy0 + 2 * t + 1);
            mN1 = ldmos(gy0 + 2 * t + 2);
            zN0 = ldnz(gy0 + 2 * t);
            zN1 = ldnz(gy0 + 2 * t + 1);
        }
        HB hn0 = hblur(mC0);                     // hblur row gy0-1+2t
        HB hn1 = hblur(mC1);                     // hblur row gy0+2t
        // noisy r0 = gy0-2+2t (even, chE=1): vblur(hc0, hc1, hn0)
        // noisy r1 = gy0-1+2t (odd,  chE=0): vblur(hc1, hn0, hn1)
        mknoisy(hc0, hc1, hn0, zC0, 1, ring[t % 3][0]);
        mknoisy(hc1, hn0, hn1, zC1, 0, ring[t % 3][1]);
        hc0 = hn0; hc1 = hn1;

        if (t >= 2) {                            // demosaic rows gy0+2t-4, +2t-3
            const int y0 = gy0 + 2 * t - 4;      // even
            float R0[4], G0[4], B0[4], R1[4], G1[4], B1[4];
            dem(ring[(t - 2) % 3][0], ring[(t - 2) % 3][1], ring[(t - 1) % 3][0],
                ring[(t - 1) % 3][1], ring[t % 3][0], false, R0, G0, B0);
            dem(ring[(t - 2) % 3][1], ring[(t - 1) % 3][0], ring[(t - 1) % 3][1],
                ring[t % 3][0], ring[t % 3][1], true, R1, G1, B1);
            // plane-major stores: 2-row contiguous bursts per plane
            size_t o = outb + (size_t)y0 * W + x0;
            *(f4u*)(out + o)              = (f4u){R0[0], R0[1], R0[2], R0[3]};
            *(f4u*)(out + o + W)          = (f4u){R1[0], R1[1], R1[2], R1[3]};
            *(f4u*)(out + o + HW)         = (f4u){G0[0], G0[1], G0[2], G0[3]};
            *(f4u*)(out + o + HW + W)     = (f4u){G1[0], G1[1], G1[2], G1[3]};
            *(f4u*)(out + o + 2 * HW)     = (f4u){B0[0], B0[1], B0[2], B0[3]};
            *(f4u*)(out + o + 2 * HW + W) = (f4u){B1[0], B1[1], B1[2], B1[3]};
        }
    }
}

extern "C" void kernel_launch(void* const* d_in, const int* in_sizes, int n_in,
                              void* d_out, int out_size, void* d_ws, size_t ws_size,
                              hipStream_t stream) {
    const float* im    = (const float*)d_in[0];
    const float* yp    = (const float*)d_in[1];
    const float* noise = (const float*)d_in[2];
    float* out = (float*)d_out;

    const int H = 512, W = 512;
    const int B = in_sizes[2] / (H * W);         // noise is (B,1,H,W)

    const int stripes = W / 256;                 // 2
    const int slots   = stripes * (H / TDS);     // 128 wave-slots per image
    dim3 grid(slots / 4, 1, B);                  // 4 waves per 256-thread block
    camera_kernel<<<grid, 256, 0, stream>>>(im, yp, noise, out, H, W);
}

// Round 14
// 40.480 us; speedup vs baseline: 2.3934x; 1.0919x over previous
//
#include <hip/hip_runtime.h>

// Camera ISP fused: mosaic -> 3x3 gauss blur -> 17-knot LUT -> +noise ->
// sparse 5x5 demosaic -> bayer-parity select -> clip.
// Round 13: R9 rolling-register pipeline (TDS=16, 1-deep prefetch) with
// 2 px/lane (float2): 4 x-stripes of 128 px -> 4096 waves (4/SIMD) at
// UNCHANGED vertical halo / HBM traffic. TLP on the x-axis is halo-free
// (halo via shfl); y-axis splits (R7/R12) paid +25-50% refetch and lost.

#define TDS 16     // output rows per wave

typedef float f2u __attribute__((ext_vector_type(2), aligned(8)));
typedef float f4u __attribute__((ext_vector_type(4), aligned(16)));

struct HB { float hb0, hb1, hh0, hh1; };
struct MR { f2u a, b; f4u ae, be; };
struct NZ { f2u z; float ze0, ze1; };

__device__ __forceinline__ int refl(int i, int n) {
    return i < 0 ? -i : (i >= n ? 2 * n - 2 - i : i);
}

__device__ __forceinline__ float clip01(float x) {
    return fminf(fmaxf(x * (1.0f / 255.0f), 0.0f), 1.0f);
}

__global__ __launch_bounds__(256, 2) void camera_kernel(
    const float* __restrict__ im, const float* __restrict__ yp,
    const float* __restrict__ noise, float* __restrict__ out,
    int H, int W)
{
    __shared__ float2 s_tab[4][48];   // per-wave LUT copy (no block barrier)

    const int tid  = threadIdx.x;
    const int wv   = tid >> 6;
    const int lane = tid & 63;
    const int b    = blockIdx.z;

    const int stripes = W >> 7;                  // 128-px stripes (4)
    const int slot    = blockIdx.x * 4 + wv;
    const int stripe  = slot % stripes;
    const int gy0     = (slot / stripes) * TDS;  // even
    const int gx0     = stripe << 7;             // even
    const int x0      = gx0 + 2 * lane;          // first owned col (even)

    const size_t HW = (size_t)H * W;
    const float* p0  = im + (size_t)b * 3 * HW;  // ch0 plane
    const float* p1  = p0 + HW;                  // ch1 plane
    const float* nzb = noise + (size_t)b * HW;

    if (lane < 48) {
        int ch = lane >> 4, i = lane & 15;
        s_tab[wv][lane] = make_float2(yp[ch * 17 + i], yp[ch * 17 + i + 1]);
    }
    asm volatile("s_waitcnt lgkmcnt(0)" ::: "memory");
    const float2* tabw = s_tab[wv];

    const bool l0   = (lane == 0), l63 = (lane == 63);
    const bool lInt = l0  && (gx0 != 0);         // interior stripe boundary
    const bool rInt = l63 && (x0 + 2 != W);
    const bool eInt = lInt || rInt;
    // edge halo bases (16B-aligned mosaic, 8B-aligned noise)
    const int  xe   = l0 ? x0 - 4 : x0 + 2;      // mosaic float4 base
    const int  xen  = l0 ? x0 - 2 : x0 + 2;      // noise float2 base

    const float g0 = 0.04038794f;   // 1D gauss tail (sigma=0.4, normalized)
    const float g1 = 0.91922413f;   // 1D gauss center

    auto itp = [&](float tv, int ch) -> float {  // LUT interp, input x16 scale
        float s = tv * 16.0f;
        int i = (int)s; i = i < 0 ? 0 : (i > 15 ? 15 : i);
        float2 p = tabw[ch * 16 + i];
        return fmaf(s - (float)i, p.y - p.x, p.x);
    };

    // ---- raw loads (issue-only) ----
    auto ldmos = [&](int t) -> MR {
        MR m;
        int yr = refl(t, H);                     // parity-preserving
        const float* pe = (t & 1) ? p0 : p1;     // plane for even cols
        const float* re = pe + (size_t)yr * W;
        const float* ro = re + HW;               // plane for odd cols
        m.a = *(const f2u*)(re + x0);            // cols x0, x0+1 (even plane)
        m.b = *(const f2u*)(ro + x0);            // cols x0, x0+1 (odd plane)
        m.ae = (f4u){0.f, 0.f, 0.f, 0.f};
        m.be = (f4u){0.f, 0.f, 0.f, 0.f};
        if (eInt) {
            m.ae = *(const f4u*)(re + xe);
            m.be = *(const f4u*)(ro + xe);
        }
        return m;
    };
    auto ldnz = [&](int t) -> NZ {
        NZ z;
        int yr = refl(t, H);
        const float* nzr = nzb + (size_t)yr * W;
        z.z = *(const f2u*)(nzr + x0);
        z.ze0 = 0.f; z.ze1 = 0.f;
        if (eInt) {
            float2 e = *(const float2*)(nzr + xen);
            z.ze0 = e.x; z.ze1 = e.y;
        }
        return z;
    };

    // ---- hblur from raw row (shfl + fma) ----
    // l0: me = cols x0-4..x0-1 ; l63: me = cols x0+2..x0+5
    auto hblur = [&](const MR& q) -> HB {
        float m0 = q.a.x, m1 = q.b.y;            // cols x0 (even), x0+1 (odd)
        float ml = __shfl_up(m1, 1, 64);         // col x0-1
        float mr = __shfl_down(m0, 1, 64);       // col x0+2
        float me0 = q.ae.x, me1 = q.be.y, me2 = q.ae.z, me3 = q.be.w;
        if (l0)  ml = lInt ? me3 : m1;           // reflect: col -1 -> 1
        if (l63) mr = rInt ? me0 : m0;           // reflect: col W -> W-2
        HB h;
        h.hb0 = fmaf(g0, ml + m1, g1 * m0);
        h.hb1 = fmaf(g0, m0 + mr, g1 * m1);
        // edge-halo hblur (l0: cols x0-2,x0-1 ; l63: cols x0+2,x0+3)
        float hL0 = fmaf(g0, me1 + me3, g1 * me2);
        float hL1 = fmaf(g0, me2 + m0,  g1 * me3);
        float hR0 = fmaf(g0, m1 + me1,  g1 * me0);
        float hR1 = fmaf(g0, me0 + me2, g1 * me1);
        h.hh0 = l0 ? hL0 : hR0;
        h.hh1 = l0 ? hL1 : hR1;
        return h;
    };

    // produce one noisy row window (cols x0-2..x0+3) into rg[6]
    auto mknoisy = [&](const HB& a, const HB& bq, const HB& c,
                       const NZ& z, int chE, float* rg) {
        float tb0 = fmaf(g0, a.hb0 + c.hb0, g1 * bq.hb0);
        float tb1 = fmaf(g0, a.hb1 + c.hb1, g1 * bq.hb1);
        float th0 = fmaf(g0, a.hh0 + c.hh0, g1 * bq.hh0);
        float th1 = fmaf(g0, a.hh1 + c.hh1, g1 * bq.hh1);
        const int chO = chE + 1;
        float c0 = itp(tb0, chE) + z.z.x;        // col x0 (even)
        float c1 = itp(tb1, chO) + z.z.y;        // col x0+1
        float e0 = 0.f, e1 = 0.f;
        if (eInt) {                              // halo cols are even,odd too
            e0 = itp(th0, chE) + z.ze0;
            e1 = itp(th1, chO) + z.ze1;
        }
        float hl0 = __shfl_up(c0, 1, 64);        // col x0-2
        float hl1 = __shfl_up(c1, 1, 64);        // col x0-1
        float hr0 = __shfl_down(c0, 1, 64);      // col x0+2
        float hr1 = __shfl_down(c1, 1, 64);      // col x0+3
        if (l0)  { hl0 = lInt ? e0 : hr0;  hl1 = lInt ? e1 : c1; }  // -2->2, -1->1
        if (l63) { hr0 = rInt ? e0 : c0;   hr1 = rInt ? e1 : hl1; } // W->W-2, W+1->W-3
        rg[0] = hl0; rg[1] = hl1; rg[2] = c0;
        rg[3] = c1;  rg[4] = hr0; rg[5] = hr1;
    };

    // demosaic 2 px from 5 noisy-row windows; yO = row parity
    auto dem = [&](const float* u2, const float* u1, const float* ct,
                   const float* d1, const float* d2, bool yO,
                   float* Rv, float* Gv, float* Bv) {
        #pragma unroll
        for (int j = 0; j < 2; ++j) {
            const int cj = 2 + j;
            float c    = ct[cj];
            float ax1x = ct[cj - 1] + ct[cj + 1];
            float ax2x = ct[cj - 2] + ct[cj + 2];
            float ax1y = u1[cj] + d1[cj];
            float diag = u1[cj - 1] + u1[cj + 1] + d1[cj - 1] + d1[cj + 1];
            float ax2y = u2[cj] + d2[cj];
            const bool xO = (j & 1) != 0;
            float R, G, Bc;
            if (!yO && !xO) {        // p00: R=v, G=raw, B=h
                float hh = (0.5f * ax2y - diag - ax2x + 4.f * ax1x + 5.f * c) * 0.125f;
                float vv = (0.5f * ax2x - diag - ax2y + 4.f * ax1y + 5.f * c) * 0.125f;
                R = vv; G = c; Bc = hh;
            } else if (!yO && xO) {  // p01: R=d, G=g, B=raw
                float gg = (2.f * (ax1y + ax1x) - ax2y - ax2x + 4.f * c) * 0.125f;
                float dd = (2.f * diag - 1.5f * (ax2y + ax2x) + 6.f * c) * 0.125f;
                R = dd; G = gg; Bc = c;
            } else if (yO && !xO) {  // p10: R=raw, G=g, B=d
                float gg = (2.f * (ax1y + ax1x) - ax2y - ax2x + 4.f * c) * 0.125f;
                float dd = (2.f * diag - 1.5f * (ax2y + ax2x) + 6.f * c) * 0.125f;
                R = c; G = gg; Bc = dd;
            } else {                 // p11: R=h, G=raw, B=v
                float hh = (0.5f * ax2y - diag - ax2x + 4.f * ax1x + 5.f * c) * 0.125f;
                float vv = (0.5f * ax2x - diag - ax2y + 4.f * ax1y + 5.f * c) * 0.125f;
                R = hh; G = c; Bc = vv;
            }
            Rv[j] = clip01(R); Gv[j] = clip01(G); Bv[j] = clip01(Bc);
        }
    };

    float ring[5][6];                            // 5 noisy rows x cols x0-2..x0+3
    HB hA = hblur(ldmos(gy0 - 3));
    HB hB = hblur(ldmos(gy0 - 2));
    MR mN = ldmos(gy0 - 1);                      // prefetch for k=0
    NZ zN = ldnz(gy0 - 2);
    const size_t outb = (size_t)b * 3 * HW;

    #pragma unroll
    for (int k = 0; k < TDS + 4; ++k) {
        const int r = gy0 - 2 + k;               // noisy row produced this iter
        MR mC = mN;                              // consume prefetched
        NZ zC = zN;
        if (k < TDS + 3) {                       // issue next-iter loads FIRST
            mN = ldmos(r + 2);
            zN = ldnz(r + 1);
        }
        HB hC = hblur(mC);
        const int chE = (k & 1) ? 0 : 1;         // row parity = k&1 (gy0 even)
        mknoisy(hA, hB, hC, zC, chE, ring[k % 5]);
        hA = hB; hB = hC;

        if (k >= 4) {                            // demosaic row y = gy0+k-4
            const int y = gy0 + k - 4;           // parity = k&1
            float Rv[2], Gv[2], Bv[2];
            dem(ring[(k - 4) % 5], ring[(k - 3) % 5], ring[(k - 2) % 5],
                ring[(k - 1) % 5], ring[k % 5], (k & 1) != 0, Rv, Gv, Bv);
            size_t o = outb + (size_t)y * W + x0;
            *(f2u*)(out + o)          = (f2u){Rv[0], Rv[1]};
            *(f2u*)(out + o + HW)     = (f2u){Gv[0], Gv[1]};
            *(f2u*)(out + o + 2 * HW) = (f2u){Bv[0], Bv[1]};
        }
    }
}

extern "C" void kernel_launch(void* const* d_in, const int* in_sizes, int n_in,
                              void* d_out, int out_size, void* d_ws, size_t ws_size,
                              hipStream_t stream) {
    const float* im    = (const float*)d_in[0];
    const float* yp    = (const float*)d_in[1];
    const float* noise = (const float*)d_in[2];
    float* out = (float*)d_out;

    const int H = 512, W = 512;
    const int B = in_sizes[2] / (H * W);         // noise is (B,1,H,W)

    const int stripes = W / 128;                 // 4
    const int slots   = stripes * (H / TDS);     // 128 wave-slots per image
    dim3 grid(slots / 4, 1, B);                  // 4 waves per 256-thread block
    camera_kernel<<<grid, 256, 0, stream>>>(im, yp, noise, out, H, W);
}